// Round 15
// baseline (1448.695 us; speedup 1.0000x reference)
//
#include <hip/hip_runtime.h>

#define H 181
#define T_LEN 1024
#define BB 2             // batch rows per block
#define NBLK 512         // 512 * 2 = 1024; TWO blocks per CU (indep. barriers)
#define NTHR 384         // 6 waves
#define KT3 3            // k-tiles of 64 -> 192 >= 181
#define FRAGB 1024       // bytes per kt fragment (64 lanes x 16 B)
#define PST 192          // unit stride (wsc, FC)
#define XSTR 1027        // x_s stride (odd -> broadcast reads conflict-free)

typedef __attribute__((ext_vector_type(4))) int intx4;

#define LOG2E 1.4426950408889634f
// Schraudolph exp2 (balanced sawtooth, |rel err| <= ~3%), clamped to [-20,14]
#define SCH_C  1064992506.0f
#define SCH_LO 897220352.0f
#define SCH_HI 1182433024.0f

__device__ __forceinline__ float exp2_fast(float g) {
    float s = fmaf(g, 8388608.0f, SCH_C);
    s = fminf(fmaxf(s, SCH_LO), SCH_HI);
    return __uint_as_float((unsigned)s);
}
__device__ __forceinline__ float rcpf(float x)   { return __builtin_amdgcn_rcpf(x); }
__device__ __forceinline__ float exp2hw(float x) { return __builtin_amdgcn_exp2f(x); }

// 512 blocks x 2 batch, 6 waves, TWO blocks co-resident per CU.
// R14's measured 835 cy/step of no-pipe-busy idle is barrier-lockstep stall;
// two independent barrier domains per CU let one block's waves issue while
// the other drains. Wave owns unit-tiles {2jt, 2jt+1} for all 3 gates
// (18 mfma_i32_16x16x64_i8/step). DPP redistribute to dense per-lane triples:
// lane = q*16 + r*4 + tau*2 + b  <-  reg r, col b of tile tau (7 row_shr
// DPPs/gate + mov). Gates: r Schraudolph, z/n exact exp, merged rcp (R14
// numerics, bit-identical). h bytes packed via row_shl DPP + perm; r==0
// leaders write one b32 into the next i8 frag buffer. One barrier/step/block.
__launch_bounds__(NTHR, 3)
__global__ void gru_i8(const float* __restrict__ x,
                       const float* __restrict__ w_ih,
                       const float* __restrict__ w_hh,
                       const float* __restrict__ b_ih,
                       const float* __restrict__ b_hh,
                       const float* __restrict__ w_fc,
                       const float* __restrict__ b_fc,
                       float* __restrict__ out) {
    __shared__ __align__(16) char  hfr_s[2 * KT3 * FRAGB];  // 6 KB i8 h dbuf
    __shared__ __align__(16) float x_s[BB * XSTR];          // 8.2 KB x; reused for FC
    __shared__ float wsc_s[3 * PST];                        // w_hh row scales

    const int tid  = threadIdx.x;
    const int jt   = tid >> 6;          // wave 0..5: unit tiles {2jt, 2jt+1}
    const int lane = tid & 63;
    const int col  = lane & 15;
    const int q    = lane >> 4;
    const int b0   = blockIdx.x * BB;

    // ---- A fragments: per-row int8 w_hh, 2 tiles x 3 gates x 3 kt ----
    intx4 afr[2][3][KT3];
    #pragma unroll
    for (int tt = 0; tt < 2; ++tt) {
        const int  mu = (2 * jt + tt) * 16 + col;
        const bool mv = (mu < H);
        #pragma unroll
        for (int g = 0; g < 3; ++g) {
            const float* wrow = w_hh + (size_t)(g * H + (mv ? mu : 0)) * H;
            float rm = 0.0f;
            if (mv) for (int k = 0; k < H; ++k) rm = fmaxf(rm, fabsf(wrow[k]));
            float s    = (rm > 1e-30f) ? rm * (1.0f / 127.0f) : 1.0f;
            float invs = 1.0f / s;
            #pragma unroll
            for (int kt = 0; kt < KT3; ++kt) {
                union { signed char c[16]; intx4 v; } uu;
                #pragma unroll
                for (int e = 0; e < 16; ++e) {
                    int k = kt * 64 + q * 16 + e;
                    float v = (mv && k < H) ? wrow[k] * invs : 0.0f;
                    v = fminf(fmaxf(rintf(v), -127.0f), 127.0f);
                    uu.c[e] = (signed char)(int)v;
                }
                afr[tt][g][kt] = uu.v;
            }
            if (q == 0) wsc_s[g * PST + mu] = s;
        }
    }

    // ---- stage x (stride 1027); zero h frag buffers ----
    for (int i = tid; i < BB * T_LEN; i += NTHR) {
        int bb = i >> 10, t = i & 1023;
        x_s[bb * XSTR + t] = x[(size_t)b0 * T_LEN + i];
    }
    {
        int* hz = (int*)hfr_s;
        for (int i = tid; i < 2 * KT3 * FRAGB / 4; i += NTHR) hz[i] = 0;
    }
    __syncthreads();   // wsc_s ready

    // ---- dense per-lane identity: lane = q*16 + r*4 + tau*2 + b ----
    const int  rr4 = (lane >> 2) & 3;           // reg index r
    const int  tau = (lane >> 1) & 1;           // tile half
    const int  b   = lane & 1;                  // batch
    const int  u   = (2 * jt + tau) * 16 + q * 4 + rr4;   // unit 0..191
    const bool jv  = (u < H);
    const float dqR = -LOG2E * wsc_s[0 * PST + u] * (1.0f / 127.0f);
    const float dqZ = -LOG2E * wsc_s[1 * PST + u] * (1.0f / 127.0f);
    const float dqN =  2.0f * LOG2E * wsc_s[2 * PST + u] * (1.0f / 127.0f);
    const float baseR = jv ? -LOG2E * (b_ih[u] + b_hh[u])             : 0.0f;
    const float baseZ = jv ? -LOG2E * (b_ih[H + u] + b_hh[H + u])     : 0.0f;
    const float baseN = jv ?  2.0f * LOG2E * b_hh[2 * H + u]          : 0.0f;
    const float wrS = jv ? -LOG2E * w_ih[u]                : 0.0f;
    const float wzS = jv ? -LOG2E * w_ih[H + u]            : 0.0f;
    const float wnS = jv ?  2.0f * LOG2E * w_ih[2 * H + u] : 0.0f;
    const float bnI = jv ?  2.0f * LOG2E * b_ih[2 * H + u] : 0.0f;
    // leader (r==0) packs units u0..u0+3 (fixed tau,b) and writes one b32
    const int u0    = (2 * jt + tau) * 16 + q * 4;
    const int woffB = (u0 >> 6) * FRAGB + (((u0 >> 4) & 3) * 16 + b) * 16 + (u0 & 15);
    const int rbase = lane * 16;

    float h = 0.0f;

    auto step = [&](const char* rb, char* wb, int t) {
        intx4 bf[KT3];
        #pragma unroll
        for (int kt = 0; kt < KT3; ++kt)
            bf[kt] = *(const intx4*)(rb + kt * FRAGB + rbase);
        intx4 ac[2][3];
        #pragma unroll
        for (int tt = 0; tt < 2; ++tt)
            #pragma unroll
            for (int g = 0; g < 3; ++g)
                ac[tt][g] = (intx4){0, 0, 0, 0};
        #pragma unroll
        for (int kt = 0; kt < KT3; ++kt)
            #pragma unroll
            for (int tt = 0; tt < 2; ++tt) {
                ac[tt][0] = __builtin_amdgcn_mfma_i32_16x16x64_i8(afr[tt][0][kt], bf[kt], ac[tt][0], 0, 0, 0);
                ac[tt][1] = __builtin_amdgcn_mfma_i32_16x16x64_i8(afr[tt][1][kt], bf[kt], ac[tt][1], 0, 0, 0);
                ac[tt][2] = __builtin_amdgcn_mfma_i32_16x16x64_i8(afr[tt][2][kt], bf[kt], ac[tt][2], 0, 0, 0);
            }

        // ---- DPP redistribute: lane q*16+r*4+tau*2+b <- reg r, col b, tile tau ----
        int v3[3];
        #pragma unroll
        for (int g = 0; g < 3; ++g) {
            int v = ac[0][g][0];                                                     // tau0 r0: lanes +0,+1
            v = __builtin_amdgcn_update_dpp(v, ac[0][g][1], 0x114, 0xF, 0x2, false); // tau0 r1 shr4
            v = __builtin_amdgcn_update_dpp(v, ac[0][g][2], 0x118, 0xF, 0x4, false); // tau0 r2 shr8
            v = __builtin_amdgcn_update_dpp(v, ac[0][g][3], 0x11C, 0xF, 0x8, false); // tau0 r3 shr12
            v = __builtin_amdgcn_update_dpp(v, ac[1][g][0], 0x112, 0xF, 0x1, false); // tau1 r0 shr2
            v = __builtin_amdgcn_update_dpp(v, ac[1][g][1], 0x116, 0xF, 0x2, false); // tau1 r1 shr6
            v = __builtin_amdgcn_update_dpp(v, ac[1][g][2], 0x11A, 0xF, 0x4, false); // tau1 r2 shr10
            v = __builtin_amdgcn_update_dpp(v, ac[1][g][3], 0x11E, 0xF, 0x8, false); // tau1 r3 shr14
            v3[g] = v;
        }

        // ---- dense dequant + gates (R14 numerics, bit-identical) ----
        float pR = fmaf((float)v3[0], dqR, baseR);
        float pZ = fmaf((float)v3[1], dqZ, baseZ);
        float pN = fmaf((float)v3[2], dqN, baseN);
        float xv = x_s[b * XSTR + t];

        float er = exp2_fast(fmaf(xv, wrS, pR));
        float ez = exp2hw(fminf(fmaf(xv, wzS, pZ), 14.0f));
        float dR = 1.0f + er, dZ = 1.0f + ez;
        float qq = rcpf(dR * dZ);
        float rr = qq * dZ, zz = qq * dR;
        float gn = fmaf(rr, pN, fmaf(xv, wnS, bnI));
        float en = exp2hw(fminf(gn, 30.0f));
        float nn = fmaf(-2.0f, rcpf(1.0f + en), 1.0f);  // tanh
        h = fmaf(zz, h - nn, nn);                        // |h|<1

        int iq = (int)rintf(h * 127.0f);
        int hq = jv ? (iq & 255) : 0;
        // ---- DPP gather (row_shl:4/8/12) + perm pack: bytes r=0..3 ----
        int t1 = __builtin_amdgcn_update_dpp(0, hq, 0x104, 0xF, 0xF, true);
        int t2 = __builtin_amdgcn_update_dpp(0, hq, 0x108, 0xF, 0xF, true);
        int t3 = __builtin_amdgcn_update_dpp(0, hq, 0x10C, 0xF, 0xF, true);
        int p01 = __builtin_amdgcn_perm(t1, hq, 0x05010400);
        int p23 = __builtin_amdgcn_perm(t3, t2, 0x05010400);
        int pk  = __builtin_amdgcn_perm(p23, p01, 0x05040100);
        if (rr4 == 0)
            *(int*)(wb + woffB) = pk;
        __syncthreads();   // the only barrier per step (per block)
    };

    char* buf0 = hfr_s;
    char* buf1 = hfr_s + KT3 * FRAGB;
    for (int t = 0; t < T_LEN; t += 2) {
        step(buf0, buf1, t);
        step(buf1, buf0, t + 1);
    }

    // ---- final FC: publish h (f32) into x_s (x done), 20 lanes reduce ----
    __syncthreads();
    x_s[b * PST + u] = h;    // u < 192 always; pads hold garbage, FC reads k<H only
    __syncthreads();
    if (tid < BB * 10) {
        int bb = tid / 10, c = tid % 10;
        float acc = b_fc[c];
        for (int k = 0; k < H; ++k)
            acc = fmaf(x_s[bb * PST + k], w_fc[c * H + k], acc);
        out[(b0 + bb) * 10 + c] = acc;
    }
}

extern "C" void kernel_launch(void* const* d_in, const int* in_sizes, int n_in,
                              void* d_out, int out_size, void* d_ws, size_t ws_size,
                              hipStream_t stream) {
    const float* x    = (const float*)d_in[0];
    const float* w_ih = (const float*)d_in[1];
    const float* w_hh = (const float*)d_in[2];
    const float* b_ih = (const float*)d_in[3];
    const float* b_hh = (const float*)d_in[4];
    const float* w_fc = (const float*)d_in[5];
    const float* b_fc = (const float*)d_in[6];
    float* out = (float*)d_out;

    gru_i8<<<NBLK, NTHR, 0, stream>>>(x, w_ih, w_hh, b_ih, b_hh, w_fc, b_fc, out);
}